// Round 5
// baseline (1873.824 us; speedup 1.0000x reference)
//
#include <hip/hip_runtime.h>

// SparseAutoencoder fused kernel (MI355X / gfx950) — fp32 wire.
// x:[B,64] enc_W:[512,64] enc_b:[512] dec_W:[64,512] dec_b:[64], all float32.
// out = [x_hat (B*64) | z_sparse (B*512)] float32.
//
// Theory of record (R7): selection must match np-float32 sgemm ranking.
// z~ via 2-MFMA (x hi/lo split x bf16 weights), |z~-z| <= EPSC*wmax*xabs.
// Candidates = all z~ >= edge(t8) - 2*eps (superset of true top-32).
// ALL candidates re-ranked with the exact fp32 sequential FMA chain.
//
// R8 changes (latency-bound at 2 waves/SIMD; VALUBusy 29%, all else idle):
//  (1) 3 blocks/CU: LDS 55.8 -> ~51.2 KB by unioning hist/fb (dead after
//      phase 3b) with cidx (live from phase 4). __launch_bounds__(256,3).
//  (2) Register budget 512/3 = 170/wave: drop bd[16] persistence (reload
//      per tile from L2-hot decW, 4x4 chunks; MFMA order unchanged ->
//      bit-identical x_hat). Peak demand ~159 (beh 64 + acc 64 + frags).
//  (3) phase-5 rank loop: fast path when mB==0 (99.95% of rows) skips the
//      B-half shfl/cmp machinery (~40% fewer ops in the hot loop).
//  Predict: Occupancy 24 -> 34%, dur -> ~900us, WRITE -> ~680MB,
//  FETCH -> ~400MB. Falsifier: occupancy stuck at 24 => regs > 168,
//  drop beh persistence next.

#define BATCH 262144
#define IND   64
#define LAT   512
#define TOPK  32
#define RPB   128   // rows per block
#define TR    32    // rows per tile
#define NTT   (RPB / TR)
#define CCAP  128   // candidate capacity per row (mean ~45, sd ~7)
#define EPSC  4.2e-3f   // 2^-8 * slack: |z~-z| <= EPSC*wmax*sum|x|
#define NB    32    // linear hist bins
#define NBPAD 36    // padded row stride (words): 16B-aligned rows

typedef __attribute__((ext_vector_type(8))) short short8;
typedef __attribute__((ext_vector_type(4))) float f32x4;

__device__ __forceinline__ unsigned short f2bf(float f) {
  unsigned u = __float_as_uint(f);
  unsigned r = ((u >> 16) & 1u) + 0x7FFFu;   // RNE
  return (unsigned short)((u + r) >> 16);
}
__device__ __forceinline__ float bfbits2f(unsigned short s) {
  return __uint_as_float(((unsigned)s) << 16);
}
// exponent-bin edges (fallback path): key = (bits>>19) - 1888; edge(1)~0.00208
__device__ __forceinline__ float edgef(int t) {
  return __uint_as_float((unsigned)(1888 + t) << 19);
}
__device__ __forceinline__ short8 pack8(float4 a, float4 b) {
  short8 r;
  r[0] = (short)f2bf(a.x); r[1] = (short)f2bf(a.y);
  r[2] = (short)f2bf(a.z); r[3] = (short)f2bf(a.w);
  r[4] = (short)f2bf(b.x); r[5] = (short)f2bf(b.y);
  r[6] = (short)f2bf(b.z); r[7] = (short)f2bf(b.w);
  return r;
}
// split v = hi + lo with hi,lo bf16; hi = bf16(v), lo = bf16(v - hi)
__device__ __forceinline__ void split8(const float* p, short8& h, short8& l) {
  #pragma unroll
  for (int i = 0; i < 8; i++) {
    float v = p[i];
    unsigned short hb = f2bf(v);
    float r = v - bfbits2f(hb);
    h[i] = (short)hb;
    l[i] = (short)f2bf(r);
  }
}
// exact np.float32 sgemm dot: sequential k=0..63, single accumulator, FMA.
// chunked loads (2 x 8 float4) cap in-flight regs; FMA ORDER PRESERVED.
__device__ __forceinline__ float exact_dot64(const float* __restrict__ wr,
                                             const float* xr) {
  float s = 0.0f;
  #pragma unroll 1
  for (int g = 0; g < 2; g++) {
    const float4 w0 = *(const float4*)(wr + 32*g);
    const float4 w1 = *(const float4*)(wr + 32*g + 4);
    const float4 w2 = *(const float4*)(wr + 32*g + 8);
    const float4 w3 = *(const float4*)(wr + 32*g + 12);
    const float4 w4 = *(const float4*)(wr + 32*g + 16);
    const float4 w5 = *(const float4*)(wr + 32*g + 20);
    const float4 w6 = *(const float4*)(wr + 32*g + 24);
    const float4 w7 = *(const float4*)(wr + 32*g + 28);
    const float* xk = xr + 32*g;
    s = fmaf(xk[0],  w0.x, s); s = fmaf(xk[1],  w0.y, s);
    s = fmaf(xk[2],  w0.z, s); s = fmaf(xk[3],  w0.w, s);
    s = fmaf(xk[4],  w1.x, s); s = fmaf(xk[5],  w1.y, s);
    s = fmaf(xk[6],  w1.z, s); s = fmaf(xk[7],  w1.w, s);
    s = fmaf(xk[8],  w2.x, s); s = fmaf(xk[9],  w2.y, s);
    s = fmaf(xk[10], w2.z, s); s = fmaf(xk[11], w2.w, s);
    s = fmaf(xk[12], w3.x, s); s = fmaf(xk[13], w3.y, s);
    s = fmaf(xk[14], w3.z, s); s = fmaf(xk[15], w3.w, s);
    s = fmaf(xk[16], w4.x, s); s = fmaf(xk[17], w4.y, s);
    s = fmaf(xk[18], w4.z, s); s = fmaf(xk[19], w4.w, s);
    s = fmaf(xk[20], w5.x, s); s = fmaf(xk[21], w5.y, s);
    s = fmaf(xk[22], w5.z, s); s = fmaf(xk[23], w5.w, s);
    s = fmaf(xk[24], w6.x, s); s = fmaf(xk[25], w6.y, s);
    s = fmaf(xk[26], w6.z, s); s = fmaf(xk[27], w6.w, s);
    s = fmaf(xk[28], w7.x, s); s = fmaf(xk[29], w7.y, s);
    s = fmaf(xk[30], w7.z, s); s = fmaf(xk[31], w7.w, s);
  }
  return s;
}

__global__ __launch_bounds__(256, 3)
void sae_fused(const float* __restrict__ xg,
               const float* __restrict__ encW,
               const float* __restrict__ encB,
               const float* __restrict__ decW,
               const float* __restrict__ decB,
               float* __restrict__ out_xhat,
               float* __restrict__ out_z)
{
  // hist (phases 1-3) / fb (3b) / cidx (4-5) never live simultaneously.
  __shared__ union {
    unsigned       hist[TR][NBPAD];   // 4.6 KB
    unsigned       fb[256];           // 1.0 KB
    unsigned short cidx[TR][CCAP];    // 8.0 KB
  } hc;
  __shared__ unsigned short zsp[TR][520];     // 33.3 KB dense z (bf16 bits)
  __shared__ float    xtile[TR][68];          // 8.7 KB fp32 x rows
  __shared__ float    rowlo[TR];
  __shared__ float    xabs[TR];
  __shared__ float    xlo0[TR];        // per-row hist floor (0.7*sigma^)
  __shared__ float    xinvw[TR];       // per-row 1/binwidth
  __shared__ float    xwid[TR];        // per-row binwidth
  __shared__ int      ccnt[TR];
  __shared__ int      degen[TR];
  __shared__ int      wmax_i;
  __shared__ int      fbmask;

  const int tid  = threadIdx.x;
  const int w    = tid >> 6;     // wave 0..3
  const int lane = tid & 63;
  const int c    = lane & 15;
  const int q    = lane >> 4;

  if (tid == 0) wmax_i = 0;
  __syncthreads();

  // ---- persistent enc_W fragments, bf16 hi ONLY (cols 128w..128w+127) ----
  short8 beh[8][2];
  float  lmax = 0.0f;
  #pragma unroll
  for (int n = 0; n < 8; n++)
    #pragma unroll
    for (int ks = 0; ks < 2; ks++) {
      const float* p = encW + (size_t)(128*w + 16*n + c)*IND + 32*ks + 8*q;
      float4 a = *(const float4*)p, b = *(const float4*)(p + 4);
      lmax = fmaxf(lmax, fmaxf(fmaxf(fabsf(a.x), fabsf(a.y)), fmaxf(fabsf(a.z), fabsf(a.w))));
      lmax = fmaxf(lmax, fmaxf(fmaxf(fabsf(b.x), fabsf(b.y)), fmaxf(fabsf(b.z), fabsf(b.w))));
      beh[n][ks] = pack8(a, b);
    }
  atomicMax(&wmax_i, __float_as_int(lmax));   // nonneg floats: int cmp == float cmp

  float ebias[8];
  #pragma unroll
  for (int n = 0; n < 8; n++) ebias[n] = encB[128*w + 16*n + c];
  const float dbias = decB[16*w + c];
  __syncthreads();
  const float wmaxf = __int_as_float(wmax_i);

  #pragma unroll 1
  for (int t = 0; t < NTT; t++) {
    const int rowbase = blockIdx.x * RPB + t * TR;

    // ---- phase 1: zero hist + zsp + control; stage x tile (nt) + stats ----
    {
      uint4 z4 = {0,0,0,0};
      uint4* hp = (uint4*)&hc.hist[0][0];           // 4608 B = 288 x 16B
      hp[tid] = z4;
      if (tid < 32) hp[256 + tid] = z4;
      uint4* zp = (uint4*)&zsp[0][0];               // 33280 B = 2080 x 16B
      #pragma unroll
      for (int i = 0; i < 8; i++) zp[tid + 256*i] = z4;
      if (tid < 32) zp[2048 + tid] = z4;
      if (tid < TR) { ccnt[tid] = 0; degen[tid] = 0; }
      if (tid == 0) fbmask = 0;
    }
    {
      const int row = tid >> 3, sub = tid & 7;      // 8 threads per row
      const f32x4* gp = (const f32x4*)(xg + (size_t)(rowbase + row)*IND) + 2*sub;
      f32x4 a = __builtin_nontemporal_load(gp);
      f32x4 b = __builtin_nontemporal_load(gp + 1);
      *(f32x4*)&xtile[row][8*sub]     = a;
      *(f32x4*)&xtile[row][8*sub + 4] = b;
      float s  = fabsf(a.x)+fabsf(a.y)+fabsf(a.z)+fabsf(a.w)
               + fabsf(b.x)+fabsf(b.y)+fabsf(b.z)+fabsf(b.w);
      float s2 = a.x*a.x+a.y*a.y+a.z*a.z+a.w*a.w
               + b.x*b.x+b.y*b.y+b.z*b.z+b.w*b.w;
      s  += __shfl_xor(s, 1);  s  += __shfl_xor(s, 2);  s  += __shfl_xor(s, 4);
      s2 += __shfl_xor(s2, 1); s2 += __shfl_xor(s2, 2); s2 += __shfl_xor(s2, 4);
      if (sub == 0) {
        xabs[row] = s;
        // z_j ~ N(0, sigma^2), sigma^ = sqrt(var(w))*||x||, var(w)=limit^2/3
        const float sig = 0.058926f * sqrtf(s2);
        xlo0[row]  = fmaxf(0.7f * sig, edgef(1));      // floor (>= tiny for deg rows)
        xwid[row]  = (2.5f / (float)NB) * sig;         // bins span [0.7,3.2]*sigma
        xinvw[row] = (float)NB / fmaxf(2.5f * sig, 1e-20f);
      }
    }
    __syncthreads();

    // ---- phase 2: 2-MFMA encode (x hi/lo x w_hi) + bias + relu; hist ----
    f32x4 acc[2][8];
    #pragma unroll
    for (int m2 = 0; m2 < 2; m2++)
      #pragma unroll
      for (int n = 0; n < 8; n++) acc[m2][n] = (f32x4){0.f,0.f,0.f,0.f};

    #pragma unroll
    for (int m2 = 0; m2 < 2; m2++) {
      const float* xr = &xtile[16*m2 + c][0];
      short8 a0h, a0l, a1h, a1l;
      split8(xr + 8*q,      a0h, a0l);
      split8(xr + 32 + 8*q, a1h, a1l);
      #pragma unroll
      for (int n = 0; n < 8; n++) {
        acc[m2][n] = __builtin_amdgcn_mfma_f32_16x16x32_bf16(a0h, beh[n][0], acc[m2][n], 0,0,0);
        acc[m2][n] = __builtin_amdgcn_mfma_f32_16x16x32_bf16(a0l, beh[n][0], acc[m2][n], 0,0,0);
        acc[m2][n] = __builtin_amdgcn_mfma_f32_16x16x32_bf16(a1h, beh[n][1], acc[m2][n], 0,0,0);
        acc[m2][n] = __builtin_amdgcn_mfma_f32_16x16x32_bf16(a1l, beh[n][1], acc[m2][n], 0,0,0);
      }
    }
    {
      float flo[2][4], fiw[2][4];
      #pragma unroll
      for (int m2 = 0; m2 < 2; m2++)
        #pragma unroll
        for (int r = 0; r < 4; r++) {
          flo[m2][r] = xlo0[16*m2 + 4*q + r];
          fiw[m2][r] = xinvw[16*m2 + 4*q + r];
        }
      #pragma unroll
      for (int m2 = 0; m2 < 2; m2++)
        #pragma unroll
        for (int n = 0; n < 8; n++)
          #pragma unroll
          for (int r = 0; r < 4; r++) {
            float v = fmaxf(acc[m2][n][r] + ebias[n], 0.0f);
            acc[m2][n][r] = v;
            if (v >= flo[m2][r]) {                       // ~24% of values
              const int row = 16*m2 + 4*q + r;
              int k = (int)((v - flo[m2][r]) * fiw[m2][r]);
              k = min(k, NB-1);
              atomicAdd(&hc.hist[row][k], 1u);
            }
          }
    }
    __syncthreads();

    // ---- phase 3: per-row boundary bin over 32 linear bins ----
    #pragma unroll 1
    for (int rr = 0; rr < 8; rr++) {
      const int row = 8*w + rr;
      uint4 h = {0,0,0,0};
      if (lane < 8) h = *(const uint4*)&hc.hist[row][4*lane];
      int T = (int)(h.x + h.y + h.z + h.w);
      int I = T;
      #pragma unroll
      for (int d = 1; d < 8; d <<= 1) {
        int t2 = __shfl_down(I, d);
        if (lane + d < 8) I += t2;
      }
      const int I0 = __shfl(I, 0);
      if (I0 < TOPK) {
        // top-32 reaches below the statistical floor (P ~ 0 for this input,
        // but must be correct): defer to exact fallback re-hist below.
        if (lane == 0) atomicOr(&fbmask, (int)(1u << row));
      } else {
        unsigned long long msk = __ballot(I >= TOPK);   // lanes>=8 have I=0
        const int ls = __popcll(msk) - 1;
        const int Il = __shfl(I, ls);
        const int hx = __shfl((int)h.x, ls);
        const int hy = __shfl((int)h.y, ls);
        const int hz = __shfl((int)h.z, ls);
        const int s1 = Il - hx, s2 = s1 - hy, s3 = s2 - hz;
        const int t8 = (s3 >= TOPK) ? 4*ls+3 : (s2 >= TOPK) ? 4*ls+2
                     : (s1 >= TOPK) ? 4*ls+1 : 4*ls;
        if (lane == 0) {
          const float eps2 = EPSC * wmaxf * xabs[row] + 1e-7f;
          rowlo[row] = fmaxf(xlo0[row] + (float)t8 * xwid[row] - 2.0f*eps2, 1e-30f);
        }
      }
    }
    __syncthreads();

    // ---- phase 3b (rare): exact 256-bin exponent re-hist for flagged rows ----
    if (fbmask) {
      unsigned* fb = &hc.fb[0];              // hist dead; cidx not yet live
      unsigned fbm = (unsigned)fbmask;
      while (fbm) {
        const int R = (int)__ffs(fbm) - 1;
        fbm &= fbm - 1;
        fb[tid] = 0;
        __syncthreads();
        if ((lane >> 4) == ((R >> 2) & 3)) {   // 64 owner threads of row R
          const int m2R = R >> 4, rR = R & 3;
          #pragma unroll
          for (int m2 = 0; m2 < 2; m2++)
            #pragma unroll
            for (int r = 0; r < 4; r++)
              if (m2 == m2R && r == rR) {      // static acc indices (no scratch)
                #pragma unroll
                for (int n = 0; n < 8; n++) {
                  float v = acc[m2][n][r];
                  int k8 = (int)(__float_as_uint(v) >> 19) - 1888;
                  k8 = max(0, min(255, k8));
                  atomicAdd(&fb[k8], 1u);
                }
              }
        }
        __syncthreads();
        if (w == 0) {
          uint4 h = *(const uint4*)&fb[4*lane];
          int T = (int)(h.x + h.y + h.z + h.w);
          int I = T;
          #pragma unroll
          for (int d = 1; d < 64; d <<= 1) {
            int t2 = __shfl_down(I, d);
            if (lane + d < 64) I += t2;
          }
          const int I0  = __shfl(I, 0);
          const int hx0 = __shfl((int)h.x, 0);
          if (I0 - hx0 < TOPK) {
            // <32 values above ~0.002: sub-threshold noise, write all >= edge(1)
            if (lane == 0) { degen[R] = 1; rowlo[R] = edgef(1); }
          } else {
            unsigned long long msk = __ballot(I >= TOPK);
            const int ls = __popcll(msk) - 1;
            const int Il = __shfl(I, ls);
            const int hx = __shfl((int)h.x, ls);
            const int hy = __shfl((int)h.y, ls);
            const int hz = __shfl((int)h.z, ls);
            const int s1 = Il - hx, s2 = s1 - hy, s3 = s2 - hz;
            const int t8 = (s3 >= TOPK) ? 4*ls+3 : (s2 >= TOPK) ? 4*ls+2
                         : (s1 >= TOPK) ? 4*ls+1 : 4*ls;
            if (lane == 0) {
              const float eps2 = EPSC * wmaxf * xabs[R] + 1e-7f;
              rowlo[R] = fmaxf(edgef(t8) - 2.0f*eps2, 1e-30f);
            }
          }
        }
        __syncthreads();
      }
    }

    // ---- phase 4: append candidate indices; degen rows scatter directly ----
    #pragma unroll
    for (int m2 = 0; m2 < 2; m2++)
      #pragma unroll
      for (int r = 0; r < 4; r++) {
        const int row = 16*m2 + 4*q + r;
        const float lo = rowlo[row];
        const int dg = degen[row];
        #pragma unroll
        for (int n = 0; n < 8; n++) {
          const float v = acc[m2][n][r];
          if (v >= lo) {
            if (dg) {
              zsp[row][128*w + 16*n + c] = f2bf(v);
            } else {
              int slot = atomicAdd(&ccnt[row], 1);
              if (slot < CCAP) hc.cidx[row][slot] = (unsigned short)(128*w + 16*n + c);
            }
          }
        }
      }
    __syncthreads();

    // ---- phase 5: ALWAYS-exact selection: recompute every candidate with
    // the np.float32 sequential FMA chain, rank exactly (tie: lower index) ----
    #pragma unroll 1
    for (int rr = 0; rr < 8; rr++) {
      const int row = 8*w + rr;
      if (degen[row]) continue;
      const int m  = min(ccnt[row], CCAP);
      const int mA = min(m, 64);
      const int mB = m - mA;                      // usually 0 (m>64 is rare)
      const float* xr = &xtile[row][0];

      int ciA = 0xFFFF; float sA = -1e30f;
      {
        const int js = (lane < mA) ? (int)hc.cidx[row][lane] : 0;
        float s = exact_dot64(encW + (size_t)js * IND, xr);
        s += encB[js];
        s = fmaxf(s, 0.0f);
        if (lane < mA) { sA = s; ciA = js; }
      }

      if (mB == 0) {
        // fast path: single-half ranking (the ~99.95% case)
        int rank0 = 0;
        for (int jj = 0; jj < mA; jj++) {
          const float vj = __shfl(sA, jj);
          const int   ij = __shfl(ciA, jj);
          rank0 += (vj > sA || (vj == sA && ij < ciA)) ? 1 : 0;
        }
        if (lane < mA && rank0 < TOPK) zsp[row][ciA] = f2bf(sA);
      } else {
        int ciB = 0xFFFF; float sB = -1e30f;
        {
          const int js = (lane < mB) ? (int)hc.cidx[row][64 + lane] : 0;
          float s = exact_dot64(encW + (size_t)js * IND, xr);
          s += encB[js];
          s = fmaxf(s, 0.0f);
          if (lane < mB) { sB = s; ciB = js; }
        }
        int rank0 = 0, rank1 = 0;
        for (int jj = 0; jj < mA; jj++) {
          const float vj = __shfl(sA, jj);
          const int   ij = __shfl(ciA, jj);
          rank0 += (vj > sA || (vj == sA && ij < ciA)) ? 1 : 0;
          rank1 += (vj > sB || (vj == sB && ij < ciB)) ? 1 : 0;
        }
        for (int jj = 0; jj < mB; jj++) {
          const float vj = __shfl(sB, jj);
          const int   ij = __shfl(ciB, jj);
          rank0 += (vj > sA || (vj == sA && ij < ciA)) ? 1 : 0;
          rank1 += (vj > sB || (vj == sB && ij < ciB)) ? 1 : 0;
        }
        if (lane < mA && rank0 < TOPK) zsp[row][ciA] = f2bf(sA);
        if (lane < mB && rank1 < TOPK) zsp[row][ciB] = f2bf(sB);
      }
    }
    __syncthreads();

    // ---- phase 6: dense z_sparse writeback (nt) + decode MFMA + x_hat ----
    #pragma unroll 1
    for (int rr = 0; rr < 8; rr++) {
      const int row = 8*w + rr;
      const unsigned short* zr = &zsp[row][8*lane];
      f32x4 o0, o1;
      o0.x = bfbits2f(zr[0]); o0.y = bfbits2f(zr[1]); o0.z = bfbits2f(zr[2]); o0.w = bfbits2f(zr[3]);
      o1.x = bfbits2f(zr[4]); o1.y = bfbits2f(zr[5]); o1.z = bfbits2f(zr[6]); o1.w = bfbits2f(zr[7]);
      f32x4* orow = (f32x4*)(out_z + (size_t)(rowbase + row)*LAT + 8*lane);
      __builtin_nontemporal_store(o0, orow);
      __builtin_nontemporal_store(o1, orow + 1);
    }
    {
      // dec_W reloaded per tile (L2-hot), chunked 4x4 so in-flight regs stay
      // low under the 170-reg budget. MFMA order ks=0..15 unchanged.
      f32x4 acc2[2];
      acc2[0] = (f32x4){0.f,0.f,0.f,0.f};
      acc2[1] = (f32x4){0.f,0.f,0.f,0.f};
      const float* pw = decW + (size_t)(16*w + c)*LAT + 8*q;
      #pragma unroll 1
      for (int g = 0; g < 4; g++) {
        short8 bd4[4];
        #pragma unroll
        for (int j = 0; j < 4; j++) {
          const float* p = pw + 32*(4*g + j);
          bd4[j] = pack8(*(const float4*)p, *(const float4*)(p + 4));
        }
        #pragma unroll
        for (int j = 0; j < 4; j++) {
          const int ks = 4*g + j;
          short8 a0 = *(const short8*)&zsp[c][32*ks + 8*q];
          short8 a1 = *(const short8*)&zsp[16 + c][32*ks + 8*q];
          acc2[0] = __builtin_amdgcn_mfma_f32_16x16x32_bf16(a0, bd4[j], acc2[0], 0,0,0);
          acc2[1] = __builtin_amdgcn_mfma_f32_16x16x32_bf16(a1, bd4[j], acc2[1], 0,0,0);
        }
      }
      #pragma unroll
      for (int m2 = 0; m2 < 2; m2++)
        #pragma unroll
        for (int r = 0; r < 4; r++)
          out_xhat[(size_t)(rowbase + 16*m2 + 4*q + r)*IND + 16*w + c] = acc2[m2][r] + dbias;
    }
    __syncthreads();  // protect LDS reuse next tile
  }
}

extern "C" void kernel_launch(void* const* d_in, const int* in_sizes, int n_in,
                              void* d_out, int out_size, void* d_ws, size_t ws_size,
                              hipStream_t stream) {
  (void)in_sizes; (void)n_in; (void)out_size; (void)d_ws; (void)ws_size;
  const float* x    = (const float*)d_in[0];
  const float* encW = (const float*)d_in[1];
  const float* encB = (const float*)d_in[2];
  const float* decW = (const float*)d_in[3];
  const float* decB = (const float*)d_in[4];
  float* out_xhat = (float*)d_out;
  float* out_z    = out_xhat + (size_t)BATCH * IND;

  dim3 grid(BATCH / RPB), block(256);
  sae_fused<<<grid, block, 0, stream>>>(x, encW, encB, decW, decB, out_xhat, out_z);
}

// Round 6
// 1502.346 us; speedup vs baseline: 1.2473x; 1.2473x over previous
//
#include <hip/hip_runtime.h>

// SparseAutoencoder fused kernel (MI355X / gfx950) — fp32 wire.
// x:[B,64] enc_W:[512,64] enc_b:[512] dec_W:[64,512] dec_b:[64], all float32.
// out = [x_hat (B*64) | z_sparse (B*512)] float32.
//
// Theory of record (R7): selection must match np-float32 sgemm ranking.
// z~ via 2-MFMA (x hi/lo split x bf16 weights), |z~-z| <= EPSC*wmax*xabs.
// Candidates = all z~ >= edge(t8) - 2*eps (superset of true top-32).
// ALL candidates re-ranked with the exact fp32 sequential FMA chain.
//
// Register-file model (R9, from R5-R8 A/B): reported VGPR_Count = arch half;
// at 2 blocks/CU budget is 128 arch + 128 AGPR. R7 overflowed arch by ~19
// dwords (161MB spill round-trip); R8's 3-block cap (168 total) overflowed
// by ~75 (302MB). R9 fits BOTH halves:
//  (1) 2 blocks/CU (launch_bounds(256,2)); keep R8's LDS union (51.2KB).
//  (2) beh[8][2] is the ONLY persistent operand block (64 AGPR). bd dropped;
//      decW reloaded per tile in phase 6 (L2-resident 131KB; R8 proved the
//      FETCH excess was spill, not decW). MFMA order unchanged.
//  (3) exact_dot64: all 16 float4 W-loads hoisted before the FMA chain
//      (acc dead in phase 5 -> 64 in-flight regs affordable); halves the
//      exposed L2-gather latency per candidate dot. FMA order preserved.
// Predict: WRITE 906 -> ~610MB (falsifier: >700 => spill model wrong),
// FETCH 482 -> ~150MB, dur -> ~1050us, occupancy ~24%.

#define BATCH 262144
#define IND   64
#define LAT   512
#define TOPK  32
#define RPB   128   // rows per block
#define TR    32    // rows per tile
#define NTT   (RPB / TR)
#define CCAP  128   // candidate capacity per row (mean ~45, sd ~7)
#define EPSC  4.2e-3f   // 2^-8 * slack: |z~-z| <= EPSC*wmax*sum|x|
#define NB    32    // linear hist bins
#define NBPAD 36    // padded row stride (words): 16B-aligned rows

typedef __attribute__((ext_vector_type(8))) short short8;
typedef __attribute__((ext_vector_type(4))) float f32x4;

__device__ __forceinline__ unsigned short f2bf(float f) {
  unsigned u = __float_as_uint(f);
  unsigned r = ((u >> 16) & 1u) + 0x7FFFu;   // RNE
  return (unsigned short)((u + r) >> 16);
}
__device__ __forceinline__ float bfbits2f(unsigned short s) {
  return __uint_as_float(((unsigned)s) << 16);
}
// exponent-bin edges (fallback path): key = (bits>>19) - 1888; edge(1)~0.00208
__device__ __forceinline__ float edgef(int t) {
  return __uint_as_float((unsigned)(1888 + t) << 19);
}
__device__ __forceinline__ short8 pack8(float4 a, float4 b) {
  short8 r;
  r[0] = (short)f2bf(a.x); r[1] = (short)f2bf(a.y);
  r[2] = (short)f2bf(a.z); r[3] = (short)f2bf(a.w);
  r[4] = (short)f2bf(b.x); r[5] = (short)f2bf(b.y);
  r[6] = (short)f2bf(b.z); r[7] = (short)f2bf(b.w);
  return r;
}
// split v = hi + lo with hi,lo bf16; hi = bf16(v), lo = bf16(v - hi)
__device__ __forceinline__ void split8(const float* p, short8& h, short8& l) {
  #pragma unroll
  for (int i = 0; i < 8; i++) {
    float v = p[i];
    unsigned short hb = f2bf(v);
    float r = v - bfbits2f(hb);
    h[i] = (short)hb;
    l[i] = (short)f2bf(r);
  }
}
// exact np.float32 sgemm dot: sequential k=0..63, single accumulator, FMA.
// All W loads hoisted (latency overlap); FMA ORDER k=0..63 PRESERVED.
__device__ __forceinline__ float exact_dot64(const float* __restrict__ wr,
                                             const float* xr) {
  float4 W[16];
  #pragma unroll
  for (int i = 0; i < 16; i++) W[i] = *(const float4*)(wr + 4*i);
  float s = 0.0f;
  #pragma unroll
  for (int i = 0; i < 16; i++) {
    const float4 xv = *(const float4*)(xr + 4*i);   // LDS b128 broadcast
    s = fmaf(xv.x, W[i].x, s);
    s = fmaf(xv.y, W[i].y, s);
    s = fmaf(xv.z, W[i].z, s);
    s = fmaf(xv.w, W[i].w, s);
  }
  return s;
}

__global__ __launch_bounds__(256, 2)
void sae_fused(const float* __restrict__ xg,
               const float* __restrict__ encW,
               const float* __restrict__ encB,
               const float* __restrict__ decW,
               const float* __restrict__ decB,
               float* __restrict__ out_xhat,
               float* __restrict__ out_z)
{
  // hist (phases 1-3) / fb (3b) / cidx (4-5) never live simultaneously.
  __shared__ union {
    unsigned       hist[TR][NBPAD];   // 4.6 KB
    unsigned       fb[256];           // 1.0 KB
    unsigned short cidx[TR][CCAP];    // 8.0 KB
  } hc;
  __shared__ unsigned short zsp[TR][520];     // 33.3 KB dense z (bf16 bits)
  __shared__ float    xtile[TR][68];          // 8.7 KB fp32 x rows
  __shared__ float    rowlo[TR];
  __shared__ float    xabs[TR];
  __shared__ float    xlo0[TR];        // per-row hist floor (0.7*sigma^)
  __shared__ float    xinvw[TR];       // per-row 1/binwidth
  __shared__ float    xwid[TR];        // per-row binwidth
  __shared__ int      ccnt[TR];
  __shared__ int      degen[TR];
  __shared__ int      wmax_i;
  __shared__ int      fbmask;

  const int tid  = threadIdx.x;
  const int w    = tid >> 6;     // wave 0..3
  const int lane = tid & 63;
  const int c    = lane & 15;
  const int q    = lane >> 4;

  if (tid == 0) wmax_i = 0;
  __syncthreads();

  // ---- persistent enc_W fragments, bf16 hi ONLY (cols 128w..128w+127) ----
  short8 beh[8][2];
  float  lmax = 0.0f;
  #pragma unroll
  for (int n = 0; n < 8; n++)
    #pragma unroll
    for (int ks = 0; ks < 2; ks++) {
      const float* p = encW + (size_t)(128*w + 16*n + c)*IND + 32*ks + 8*q;
      float4 a = *(const float4*)p, b = *(const float4*)(p + 4);
      lmax = fmaxf(lmax, fmaxf(fmaxf(fabsf(a.x), fabsf(a.y)), fmaxf(fabsf(a.z), fabsf(a.w))));
      lmax = fmaxf(lmax, fmaxf(fmaxf(fabsf(b.x), fabsf(b.y)), fmaxf(fabsf(b.z), fabsf(b.w))));
      beh[n][ks] = pack8(a, b);
    }
  atomicMax(&wmax_i, __float_as_int(lmax));   // nonneg floats: int cmp == float cmp

  float ebias[8];
  #pragma unroll
  for (int n = 0; n < 8; n++) ebias[n] = encB[128*w + 16*n + c];
  const float dbias = decB[16*w + c];
  __syncthreads();
  const float wmaxf = __int_as_float(wmax_i);

  #pragma unroll 1
  for (int t = 0; t < NTT; t++) {
    const int rowbase = blockIdx.x * RPB + t * TR;

    // ---- phase 1: zero hist + zsp + control; stage x tile (nt) + stats ----
    {
      uint4 z4 = {0,0,0,0};
      uint4* hp = (uint4*)&hc.hist[0][0];           // 4608 B = 288 x 16B
      hp[tid] = z4;
      if (tid < 32) hp[256 + tid] = z4;
      uint4* zp = (uint4*)&zsp[0][0];               // 33280 B = 2080 x 16B
      #pragma unroll
      for (int i = 0; i < 8; i++) zp[tid + 256*i] = z4;
      if (tid < 32) zp[2048 + tid] = z4;
      if (tid < TR) { ccnt[tid] = 0; degen[tid] = 0; }
      if (tid == 0) fbmask = 0;
    }
    {
      const int row = tid >> 3, sub = tid & 7;      // 8 threads per row
      const f32x4* gp = (const f32x4*)(xg + (size_t)(rowbase + row)*IND) + 2*sub;
      f32x4 a = __builtin_nontemporal_load(gp);
      f32x4 b = __builtin_nontemporal_load(gp + 1);
      *(f32x4*)&xtile[row][8*sub]     = a;
      *(f32x4*)&xtile[row][8*sub + 4] = b;
      float s  = fabsf(a.x)+fabsf(a.y)+fabsf(a.z)+fabsf(a.w)
               + fabsf(b.x)+fabsf(b.y)+fabsf(b.z)+fabsf(b.w);
      float s2 = a.x*a.x+a.y*a.y+a.z*a.z+a.w*a.w
               + b.x*b.x+b.y*b.y+b.z*b.z+b.w*b.w;
      s  += __shfl_xor(s, 1);  s  += __shfl_xor(s, 2);  s  += __shfl_xor(s, 4);
      s2 += __shfl_xor(s2, 1); s2 += __shfl_xor(s2, 2); s2 += __shfl_xor(s2, 4);
      if (sub == 0) {
        xabs[row] = s;
        // z_j ~ N(0, sigma^2), sigma^ = sqrt(var(w))*||x||, var(w)=limit^2/3
        const float sig = 0.058926f * sqrtf(s2);
        xlo0[row]  = fmaxf(0.7f * sig, edgef(1));      // floor (>= tiny for deg rows)
        xwid[row]  = (2.5f / (float)NB) * sig;         // bins span [0.7,3.2]*sigma
        xinvw[row] = (float)NB / fmaxf(2.5f * sig, 1e-20f);
      }
    }
    __syncthreads();

    // ---- phase 2: 2-MFMA encode (x hi/lo x w_hi) + bias + relu; hist ----
    f32x4 acc[2][8];
    #pragma unroll
    for (int m2 = 0; m2 < 2; m2++)
      #pragma unroll
      for (int n = 0; n < 8; n++) acc[m2][n] = (f32x4){0.f,0.f,0.f,0.f};

    #pragma unroll
    for (int m2 = 0; m2 < 2; m2++) {
      const float* xr = &xtile[16*m2 + c][0];
      short8 a0h, a0l, a1h, a1l;
      split8(xr + 8*q,      a0h, a0l);
      split8(xr + 32 + 8*q, a1h, a1l);
      #pragma unroll
      for (int n = 0; n < 8; n++) {
        acc[m2][n] = __builtin_amdgcn_mfma_f32_16x16x32_bf16(a0h, beh[n][0], acc[m2][n], 0,0,0);
        acc[m2][n] = __builtin_amdgcn_mfma_f32_16x16x32_bf16(a0l, beh[n][0], acc[m2][n], 0,0,0);
        acc[m2][n] = __builtin_amdgcn_mfma_f32_16x16x32_bf16(a1h, beh[n][1], acc[m2][n], 0,0,0);
        acc[m2][n] = __builtin_amdgcn_mfma_f32_16x16x32_bf16(a1l, beh[n][1], acc[m2][n], 0,0,0);
      }
    }
    {
      float flo[2][4], fiw[2][4];
      #pragma unroll
      for (int m2 = 0; m2 < 2; m2++)
        #pragma unroll
        for (int r = 0; r < 4; r++) {
          flo[m2][r] = xlo0[16*m2 + 4*q + r];
          fiw[m2][r] = xinvw[16*m2 + 4*q + r];
        }
      #pragma unroll
      for (int m2 = 0; m2 < 2; m2++)
        #pragma unroll
        for (int n = 0; n < 8; n++)
          #pragma unroll
          for (int r = 0; r < 4; r++) {
            float v = fmaxf(acc[m2][n][r] + ebias[n], 0.0f);
            acc[m2][n][r] = v;
            if (v >= flo[m2][r]) {                       // ~24% of values
              const int row = 16*m2 + 4*q + r;
              int k = (int)((v - flo[m2][r]) * fiw[m2][r]);
              k = min(k, NB-1);
              atomicAdd(&hc.hist[row][k], 1u);
            }
          }
    }
    __syncthreads();

    // ---- phase 3: per-row boundary bin over 32 linear bins ----
    #pragma unroll 1
    for (int rr = 0; rr < 8; rr++) {
      const int row = 8*w + rr;
      uint4 h = {0,0,0,0};
      if (lane < 8) h = *(const uint4*)&hc.hist[row][4*lane];
      int T = (int)(h.x + h.y + h.z + h.w);
      int I = T;
      #pragma unroll
      for (int d = 1; d < 8; d <<= 1) {
        int t2 = __shfl_down(I, d);
        if (lane + d < 8) I += t2;
      }
      const int I0 = __shfl(I, 0);
      if (I0 < TOPK) {
        // top-32 reaches below the statistical floor (P ~ 0 for this input,
        // but must be correct): defer to exact fallback re-hist below.
        if (lane == 0) atomicOr(&fbmask, (int)(1u << row));
      } else {
        unsigned long long msk = __ballot(I >= TOPK);   // lanes>=8 have I=0
        const int ls = __popcll(msk) - 1;
        const int Il = __shfl(I, ls);
        const int hx = __shfl((int)h.x, ls);
        const int hy = __shfl((int)h.y, ls);
        const int hz = __shfl((int)h.z, ls);
        const int s1 = Il - hx, s2 = s1 - hy, s3 = s2 - hz;
        const int t8 = (s3 >= TOPK) ? 4*ls+3 : (s2 >= TOPK) ? 4*ls+2
                     : (s1 >= TOPK) ? 4*ls+1 : 4*ls;
        if (lane == 0) {
          const float eps2 = EPSC * wmaxf * xabs[row] + 1e-7f;
          rowlo[row] = fmaxf(xlo0[row] + (float)t8 * xwid[row] - 2.0f*eps2, 1e-30f);
        }
      }
    }
    __syncthreads();

    // ---- phase 3b (rare): exact 256-bin exponent re-hist for flagged rows ----
    if (fbmask) {
      unsigned* fb = &hc.fb[0];              // hist dead; cidx not yet live
      unsigned fbm = (unsigned)fbmask;
      while (fbm) {
        const int R = (int)__ffs(fbm) - 1;
        fbm &= fbm - 1;
        fb[tid] = 0;
        __syncthreads();
        if ((lane >> 4) == ((R >> 2) & 3)) {   // 64 owner threads of row R
          const int m2R = R >> 4, rR = R & 3;
          #pragma unroll
          for (int m2 = 0; m2 < 2; m2++)
            #pragma unroll
            for (int r = 0; r < 4; r++)
              if (m2 == m2R && r == rR) {      // static acc indices (no scratch)
                #pragma unroll
                for (int n = 0; n < 8; n++) {
                  float v = acc[m2][n][r];
                  int k8 = (int)(__float_as_uint(v) >> 19) - 1888;
                  k8 = max(0, min(255, k8));
                  atomicAdd(&fb[k8], 1u);
                }
              }
        }
        __syncthreads();
        if (w == 0) {
          uint4 h = *(const uint4*)&fb[4*lane];
          int T = (int)(h.x + h.y + h.z + h.w);
          int I = T;
          #pragma unroll
          for (int d = 1; d < 64; d <<= 1) {
            int t2 = __shfl_down(I, d);
            if (lane + d < 64) I += t2;
          }
          const int I0  = __shfl(I, 0);
          const int hx0 = __shfl((int)h.x, 0);
          if (I0 - hx0 < TOPK) {
            // <32 values above ~0.002: sub-threshold noise, write all >= edge(1)
            if (lane == 0) { degen[R] = 1; rowlo[R] = edgef(1); }
          } else {
            unsigned long long msk = __ballot(I >= TOPK);
            const int ls = __popcll(msk) - 1;
            const int Il = __shfl(I, ls);
            const int hx = __shfl((int)h.x, ls);
            const int hy = __shfl((int)h.y, ls);
            const int hz = __shfl((int)h.z, ls);
            const int s1 = Il - hx, s2 = s1 - hy, s3 = s2 - hz;
            const int t8 = (s3 >= TOPK) ? 4*ls+3 : (s2 >= TOPK) ? 4*ls+2
                         : (s1 >= TOPK) ? 4*ls+1 : 4*ls;
            if (lane == 0) {
              const float eps2 = EPSC * wmaxf * xabs[R] + 1e-7f;
              rowlo[R] = fmaxf(edgef(t8) - 2.0f*eps2, 1e-30f);
            }
          }
        }
        __syncthreads();
      }
    }

    // ---- phase 4: append candidate indices; degen rows scatter directly ----
    #pragma unroll
    for (int m2 = 0; m2 < 2; m2++)
      #pragma unroll
      for (int r = 0; r < 4; r++) {
        const int row = 16*m2 + 4*q + r;
        const float lo = rowlo[row];
        const int dg = degen[row];
        #pragma unroll
        for (int n = 0; n < 8; n++) {
          const float v = acc[m2][n][r];
          if (v >= lo) {
            if (dg) {
              zsp[row][128*w + 16*n + c] = f2bf(v);
            } else {
              int slot = atomicAdd(&ccnt[row], 1);
              if (slot < CCAP) hc.cidx[row][slot] = (unsigned short)(128*w + 16*n + c);
            }
          }
        }
      }
    __syncthreads();

    // ---- phase 5: ALWAYS-exact selection: recompute every candidate with
    // the np.float32 sequential FMA chain, rank exactly (tie: lower index) ----
    #pragma unroll 1
    for (int rr = 0; rr < 8; rr++) {
      const int row = 8*w + rr;
      if (degen[row]) continue;
      const int m  = min(ccnt[row], CCAP);
      const int mA = min(m, 64);
      const int mB = m - mA;                      // usually 0 (m>64 is rare)
      const float* xr = &xtile[row][0];

      int ciA = 0xFFFF; float sA = -1e30f;
      {
        const int js = (lane < mA) ? (int)hc.cidx[row][lane] : 0;
        float s = exact_dot64(encW + (size_t)js * IND, xr);
        s += encB[js];
        s = fmaxf(s, 0.0f);
        if (lane < mA) { sA = s; ciA = js; }
      }

      if (mB == 0) {
        // fast path: single-half ranking (the ~99.95% case)
        int rank0 = 0;
        for (int jj = 0; jj < mA; jj++) {
          const float vj = __shfl(sA, jj);
          const int   ij = __shfl(ciA, jj);
          rank0 += (vj > sA || (vj == sA && ij < ciA)) ? 1 : 0;
        }
        if (lane < mA && rank0 < TOPK) zsp[row][ciA] = f2bf(sA);
      } else {
        int ciB = 0xFFFF; float sB = -1e30f;
        {
          const int js = (lane < mB) ? (int)hc.cidx[row][64 + lane] : 0;
          float s = exact_dot64(encW + (size_t)js * IND, xr);
          s += encB[js];
          s = fmaxf(s, 0.0f);
          if (lane < mB) { sB = s; ciB = js; }
        }
        int rank0 = 0, rank1 = 0;
        for (int jj = 0; jj < mA; jj++) {
          const float vj = __shfl(sA, jj);
          const int   ij = __shfl(ciA, jj);
          rank0 += (vj > sA || (vj == sA && ij < ciA)) ? 1 : 0;
          rank1 += (vj > sB || (vj == sB && ij < ciB)) ? 1 : 0;
        }
        for (int jj = 0; jj < mB; jj++) {
          const float vj = __shfl(sB, jj);
          const int   ij = __shfl(ciB, jj);
          rank0 += (vj > sA || (vj == sA && ij < ciA)) ? 1 : 0;
          rank1 += (vj > sB || (vj == sB && ij < ciB)) ? 1 : 0;
        }
        if (lane < mA && rank0 < TOPK) zsp[row][ciA] = f2bf(sA);
        if (lane < mB && rank1 < TOPK) zsp[row][ciB] = f2bf(sB);
      }
    }
    __syncthreads();

    // ---- phase 6: dense z_sparse writeback (nt) + decode MFMA + x_hat ----
    #pragma unroll 1
    for (int rr = 0; rr < 8; rr++) {
      const int row = 8*w + rr;
      const unsigned short* zr = &zsp[row][8*lane];
      f32x4 o0, o1;
      o0.x = bfbits2f(zr[0]); o0.y = bfbits2f(zr[1]); o0.z = bfbits2f(zr[2]); o0.w = bfbits2f(zr[3]);
      o1.x = bfbits2f(zr[4]); o1.y = bfbits2f(zr[5]); o1.z = bfbits2f(zr[6]); o1.w = bfbits2f(zr[7]);
      f32x4* orow = (f32x4*)(out_z + (size_t)(rowbase + row)*LAT + 8*lane);
      __builtin_nontemporal_store(o0, orow);
      __builtin_nontemporal_store(o1, orow + 1);
    }
    {
      // dec_W reloaded per tile (L2-resident 131KB), chunked 4x4 so in-flight
      // regs stay within the arch half. MFMA order ks=0..15 unchanged.
      f32x4 acc2[2];
      acc2[0] = (f32x4){0.f,0.f,0.f,0.f};
      acc2[1] = (f32x4){0.f,0.f,0.f,0.f};
      const float* pw = decW + (size_t)(16*w + c)*LAT + 8*q;
      #pragma unroll 1
      for (int g = 0; g < 4; g++) {
        short8 bd4[4];
        #pragma unroll
        for (int j = 0; j < 4; j++) {
          const float* p = pw + 32*(4*g + j);
          bd4[j] = pack8(*(const float4*)p, *(const float4*)(p + 4));
        }
        #pragma unroll
        for (int j = 0; j < 4; j++) {
          const int ks = 4*g + j;
          short8 a0 = *(const short8*)&zsp[c][32*ks + 8*q];
          short8 a1 = *(const short8*)&zsp[16 + c][32*ks + 8*q];
          acc2[0] = __builtin_amdgcn_mfma_f32_16x16x32_bf16(a0, bd4[j], acc2[0], 0,0,0);
          acc2[1] = __builtin_amdgcn_mfma_f32_16x16x32_bf16(a1, bd4[j], acc2[1], 0,0,0);
        }
      }
      #pragma unroll
      for (int m2 = 0; m2 < 2; m2++)
        #pragma unroll
        for (int r = 0; r < 4; r++)
          out_xhat[(size_t)(rowbase + 16*m2 + 4*q + r)*IND + 16*w + c] = acc2[m2][r] + dbias;
    }
    __syncthreads();  // protect LDS reuse next tile
  }
}

extern "C" void kernel_launch(void* const* d_in, const int* in_sizes, int n_in,
                              void* d_out, int out_size, void* d_ws, size_t ws_size,
                              hipStream_t stream) {
  (void)in_sizes; (void)n_in; (void)out_size; (void)d_ws; (void)ws_size;
  const float* x    = (const float*)d_in[0];
  const float* encW = (const float*)d_in[1];
  const float* encB = (const float*)d_in[2];
  const float* decW = (const float*)d_in[3];
  const float* decB = (const float*)d_in[4];
  float* out_xhat = (float*)d_out;
  float* out_z    = out_xhat + (size_t)BATCH * IND;

  dim3 grid(BATCH / RPB), block(256);
  sae_fused<<<grid, block, 0, stream>>>(x, encW, encB, decW, decB, out_xhat, out_z);
}